// Round 3
// baseline (828.523 us; speedup 1.0000x reference)
//
#include <hip/hip_runtime.h>

#define CC 96
#define SS 16
#define GG 6
#define BN_INV 0.99999500003749969f  // 1/sqrt(1+1e-5)

// ---------------- kernel 0: tiny precompute ----------------
// Wp2T[c][j] = Wp2[j][c]                      (fp32)
// WpwT[g][j] = sum_c Wp2[j][c]*Ww1[c][g]      (= (Wp2@Ww1)^T)
// cvec[g]    = sum_c bp2[c]*Ww1[c][g] + bw1[g]
__global__ __launch_bounds__(256) void precompute_kernel(
    const float* __restrict__ Wp2, const float* __restrict__ Ww1,
    const float* __restrict__ bp2, const float* __restrict__ bw1,
    float* __restrict__ Wp2T, float* __restrict__ WpwT, float* __restrict__ cvec)
{
    int t = blockIdx.x * 256 + threadIdx.x;
    if (t < CC * CC) {
        int c = t / CC, j = t % CC;
        Wp2T[c * CC + j] = Wp2[j * CC + c];
    } else if (t < CC * CC + GG * CC) {
        int e = t - CC * CC;
        int g = e / CC, j = e % CC;
        float acc = 0.f;
        for (int c = 0; c < CC; ++c)
            acc = fmaf(Wp2[j * CC + c], Ww1[c * GG + g], acc);
        WpwT[g * CC + j] = acc;
    } else if (t < CC * CC + GG * CC + GG) {
        int g = t - (CC * CC + GG * CC);
        float acc = bw1[g];
        for (int c = 0; c < CC; ++c)
            acc = fmaf(bp2[c], Ww1[c * GG + g], acc);
        cvec[g] = acc;
    }
}

// ---------------- kernel 1: q/k/v projection ----------------
// v_ws[n][c] = feat@Wv + bv  (fp32)
// KW1[n][g]  = (relu(bn(feat@Wk+bk)))@Ww1   (fp32, rows padded to 8)
// qW1[n][g]  = (relu(bn(feat@Wq+bq)))@Ww1
__global__ __launch_bounds__(192) void qkv_kernel(
    const float* __restrict__ feat,
    const float* __restrict__ Wq, const float* __restrict__ bq, const float* __restrict__ gq, const float* __restrict__ betaq,
    const float* __restrict__ Wk, const float* __restrict__ bk, const float* __restrict__ gk, const float* __restrict__ betak,
    const float* __restrict__ Wv, const float* __restrict__ bv,
    const float* __restrict__ Ww1,
    float* __restrict__ v_ws, float* __restrict__ KW1, float* __restrict__ qW1, int N)
{
    __shared__ float sq[2][CC];
    __shared__ float sk[2][CC];
    const int tid = threadIdx.x;
    const int p = tid / CC, c = tid % CC;
    const int n = blockIdx.x * 2 + p;
    if (n < N) {
        const float* fr = feat + (size_t)n * CC;
        float aq = 0.f, ak = 0.f, av = 0.f;
        #pragma unroll 4
        for (int j = 0; j < CC; ++j) {
            float f = fr[j];
            aq = fmaf(f, Wq[j * CC + c], aq);
            ak = fmaf(f, Wk[j * CC + c], ak);
            av = fmaf(f, Wv[j * CC + c], av);
        }
        float qv = fmaxf(0.f, fmaf(aq + bq[c], gq[c] * BN_INV, betaq[c]));
        float kv = fmaxf(0.f, fmaf(ak + bk[c], gk[c] * BN_INV, betak[c]));
        v_ws[(size_t)n * CC + c] = av + bv[c];
        sq[p][c] = qv;
        sk[p][c] = kv;
    }
    __syncthreads();
    if (tid < 24) {
        const int p2 = tid / 12, which = (tid % 12) / 6, g = tid % 6;
        const int n2 = blockIdx.x * 2 + p2;
        if (n2 < N) {
            const float* src = which ? sq[p2] : sk[p2];
            float acc = 0.f;
            #pragma unroll 4
            for (int cc = 0; cc < CC; ++cc)
                acc = fmaf(src[cc], Ww1[cc * GG + g], acc);
            if (which) qW1[(size_t)n2 * 8 + g] = acc;
            else       KW1[(size_t)n2 * 8 + g] = acc;
        }
    }
}

// ---------------- kernel 2: per-point attention (1 block of 128 = 1 point) ----------------
// Conservative version: __syncthreads() between all stages, simple thread mappings.
__global__ __launch_bounds__(128) void attn_kernel(
    const float* __restrict__ coord, const int* __restrict__ ref,
    const float* __restrict__ Wp1, const float* __restrict__ bp1, const float* __restrict__ gp, const float* __restrict__ betap,
    const float* __restrict__ bp2,
    const float* __restrict__ gw, const float* __restrict__ betaw,
    const float* __restrict__ Ww2, const float* __restrict__ bw2,
    const float* __restrict__ v_ws, const float* __restrict__ KW1, const float* __restrict__ qW1,
    const float* __restrict__ WpwT, const float* __restrict__ cvec, const float* __restrict__ Wp2T,
    float* __restrict__ out, int N)
{
    __shared__ float sh[SS][100];    // h[s][c], rows padded
    __shared__ float sa[SS][8];      // stage-A activations a6[s][g]
    __shared__ float swt[SS][8];     // logits, then softmax weights
    __shared__ float sHs[GG][100];   // Hsum[g][c]
    __shared__ float spos[SS][4];    // relative positions
    __shared__ int   sidx[SS];       // neighbor indices

    const int t = threadIdx.x;
    const int n = blockIdx.x;        // grid = N exactly

    // stage 0: indices + relative positions
    if (t < SS) {
        int j = ref[n * SS + t];
        sidx[t] = j;
        float cx = coord[n * 3 + 0];
        float cy = coord[n * 3 + 1];
        float cz = coord[n * 3 + 2];
        spos[t][0] = coord[j * 3 + 0] - cx;
        spos[t][1] = coord[j * 3 + 1] - cy;
        spos[t][2] = coord[j * 3 + 2] - cz;
    }
    __syncthreads();

    // stage 1: h[s][c] = relu(bn(pos@Wp1 + bp1))
    if (t < CC) {
        const int c = t;
        const float w1x = Wp1[0 * CC + c];
        const float w1y = Wp1[1 * CC + c];
        const float w1z = Wp1[2 * CC + c];
        const float b1 = bp1[c];
        const float sp = gp[c] * BN_INV;
        const float bt = betap[c];
        #pragma unroll 4
        for (int s = 0; s < SS; ++s) {
            float h = fmaf(spos[s][0], w1x, fmaf(spos[s][1], w1y, fmaf(spos[s][2], w1z, b1)));
            sh[s][c] = fmaxf(0.f, fmaf(h, sp, bt));
        }
    }
    __syncthreads();

    // stage 2: a6[s][g] = relu(bn( h[s]@Wpw + KW1[j] - qW1[n] + cvec ))
    if (t < SS * GG) {
        const int s = t / GG, g = t % GG;
        const float* wr = WpwT + g * CC;
        const float* hr = sh[s];
        float a = 0.f;
        #pragma unroll 8
        for (int c = 0; c < CC; ++c)
            a = fmaf(hr[c], wr[c], a);
        const int jj = sidx[s];
        float tv = a + KW1[(size_t)jj * 8 + g] - qW1[(size_t)n * 8 + g] + cvec[g];
        sa[s][g] = fmaxf(0.f, fmaf(tv, gw[g] * BN_INV, betaw[g]));
    }
    __syncthreads();

    // stage 3: logits[s][g] = a6[s]@Ww2 + bw2
    if (t < SS * GG) {
        const int s = t / GG, g = t % GG;
        float l = bw2[g];
        #pragma unroll
        for (int g2 = 0; g2 < GG; ++g2)
            l = fmaf(sa[s][g2], Ww2[g2 * GG + g], l);
        swt[s][g] = l;
    }
    __syncthreads();

    // stage 4: softmax over s per g
    if (t < GG) {
        const int g = t;
        float m = -1e30f;
        #pragma unroll
        for (int s = 0; s < SS; ++s) m = fmaxf(m, swt[s][g]);
        float e[SS];
        float sum = 0.f;
        #pragma unroll
        for (int s = 0; s < SS; ++s) { e[s] = __expf(swt[s][g] - m); sum += e[s]; }
        float r = 1.f / sum;
        #pragma unroll
        for (int s = 0; s < SS; ++s) swt[s][g] = e[s] * r;
    }
    __syncthreads();

    // stage 5: Hsum[g][c] = sum_s w[s][g] * h[s][c]
    if (t < CC) {
        const int c = t;
        float hs[GG] = {0.f, 0.f, 0.f, 0.f, 0.f, 0.f};
        for (int s = 0; s < SS; ++s) {
            float hv = sh[s][c];
            #pragma unroll
            for (int g = 0; g < GG; ++g)
                hs[g] = fmaf(swt[s][g], hv, hs[g]);
        }
        #pragma unroll
        for (int g = 0; g < GG; ++g) sHs[g][c] = hs[g];
    }
    __syncthreads();

    // stage 6: out[c] = sum_s v[j_s][c]*w[s][g(c)] + Hsum[g(c)]@Wp2[:,c] + bp2[c]
    if (t < CC) {
        const int c = t;
        const int g = c >> 4;   // C/G = 16
        float acc = bp2[c];
        for (int s = 0; s < SS; ++s)
            acc = fmaf(v_ws[(size_t)sidx[s] * CC + c], swt[s][g], acc);
        const float* hr = sHs[g];
        const float* wr = Wp2T + (size_t)c * CC;
        #pragma unroll 8
        for (int j2 = 0; j2 < CC; ++j2)
            acc = fmaf(hr[j2], wr[j2], acc);
        out[(size_t)n * CC + c] = acc;
    }
}

extern "C" void kernel_launch(void* const* d_in, const int* in_sizes, int n_in,
                              void* d_out, int out_size, void* d_ws, size_t ws_size,
                              hipStream_t stream) {
    const float* feat  = (const float*)d_in[0];
    const float* coord = (const float*)d_in[1];
    const int*   ref   = (const int*)d_in[2];
    const float* Wq = (const float*)d_in[3],  *bq = (const float*)d_in[4],  *gq = (const float*)d_in[5],  *betaq = (const float*)d_in[6];
    const float* Wk = (const float*)d_in[7],  *bk = (const float*)d_in[8],  *gk = (const float*)d_in[9],  *betak = (const float*)d_in[10];
    const float* Wv = (const float*)d_in[11], *bv = (const float*)d_in[12];
    const float* Wp1 = (const float*)d_in[13], *bp1 = (const float*)d_in[14], *gp = (const float*)d_in[15], *betap = (const float*)d_in[16];
    const float* Wp2 = (const float*)d_in[17], *bp2 = (const float*)d_in[18];
    const float* Ww1 = (const float*)d_in[19], *bw1 = (const float*)d_in[20], *gw = (const float*)d_in[21], *betaw = (const float*)d_in[22];
    const float* Ww2 = (const float*)d_in[23], *bw2 = (const float*)d_in[24];

    const int N = in_sizes[0] / CC;   // 50000

    // workspace layout (fp32 throughout, ~23 MB total)
    float* wsf  = (float*)d_ws;
    float* KW1  = wsf;                               // N*8
    float* qW1  = KW1 + (size_t)N * 8;               // N*8
    float* WpwT = qW1 + (size_t)N * 8;               // 6*96
    float* cvec = WpwT + GG * CC;                    // 6 (pad to 32)
    float* Wp2T = cvec + 32;                         // 96*96
    float* v_ws = Wp2T + CC * CC;                    // N*96

    const int pre_total = CC * CC + GG * CC + GG;
    precompute_kernel<<<dim3((pre_total + 255) / 256), dim3(256), 0, stream>>>(
        Wp2, Ww1, bp2, bw1, Wp2T, WpwT, cvec);

    qkv_kernel<<<dim3((N + 1) / 2), dim3(192), 0, stream>>>(
        feat, Wq, bq, gq, betaq, Wk, bk, gk, betak, Wv, bv, Ww1,
        v_ws, KW1, qW1, N);

    attn_kernel<<<dim3(N), dim3(128), 0, stream>>>(
        coord, ref, Wp1, bp1, gp, betap, bp2, gw, betaw, Ww2, bw2,
        v_ws, KW1, qW1, WpwT, cvec, Wp2T, (float*)d_out, N);
}

// Round 4
// 491.773 us; speedup vs baseline: 1.6848x; 1.6848x over previous
//
#include <hip/hip_runtime.h>

#define CC 96
#define SS 16
#define GG 6
#define TP 32   // points per qkv block
#define BN_INV 0.99999500003749969f  // 1/sqrt(1+1e-5)

// ---------------- kernel 0: tiny precompute ----------------
// WpwT[g][j] = sum_c Wp2[j][c]*Ww1[c][g]      (= (Wp2@Ww1)^T, rows of 96)
// cvec[g]    = sum_c bp2[c]*Ww1[c][g] + bw1[g]
__global__ __launch_bounds__(256) void precompute_kernel(
    const float* __restrict__ Wp2, const float* __restrict__ Ww1,
    const float* __restrict__ bp2, const float* __restrict__ bw1,
    float* __restrict__ WpwT, float* __restrict__ cvec)
{
    int t = blockIdx.x * 256 + threadIdx.x;
    if (t < GG * CC) {
        int g = t / CC, j = t % CC;
        float acc = 0.f;
        for (int c = 0; c < CC; ++c)
            acc = fmaf(Wp2[j * CC + c], Ww1[c * GG + g], acc);
        WpwT[g * CC + j] = acc;
    } else if (t < GG * CC + GG) {
        int g = t - GG * CC;
        float acc = bw1[g];
        for (int c = 0; c < CC; ++c)
            acc = fmaf(bp2[c], Ww1[c * GG + g], acc);
        cvec[g] = acc;
    }
}

// ---------------- kernel 1: q/k/v projection, LDS-tiled ----------------
// 256 threads, 32 points/block, 3 phases sharing one LDS weight buffer.
// thread t: p = t>>3 (point), cg = t&7 (channel group of 12).
__global__ __launch_bounds__(256) void qkv_kernel(
    const float* __restrict__ feat,
    const float* __restrict__ Wq, const float* __restrict__ bq, const float* __restrict__ gq, const float* __restrict__ betaq,
    const float* __restrict__ Wk, const float* __restrict__ bk, const float* __restrict__ gk, const float* __restrict__ betak,
    const float* __restrict__ Wv, const float* __restrict__ bv,
    const float* __restrict__ Ww1,
    float* __restrict__ v_ws, float* __restrict__ KW1, float* __restrict__ qW1, int N)
{
    __shared__ __align__(16) float sfeat[TP * 100];
    __shared__ __align__(16) float sW[CC * 100];
    __shared__ __align__(16) float sout[TP * 100];

    const int t = threadIdx.x;
    const int pbase = blockIdx.x * TP;

    // stage feat tile (float4, coalesced; rows padded to 100 for bank spread)
    for (int i = t; i < TP * 24; i += 256) {
        int i4 = i * 4;
        int p = i4 / CC, j = i4 % CC;
        float4 val = make_float4(0.f, 0.f, 0.f, 0.f);
        if (pbase + p < N)
            val = *(const float4*)(feat + (size_t)(pbase + p) * CC + j);
        *(float4*)(sfeat + p * 100 + j) = val;
    }

    const int p = t >> 3, cg = t & 7, c0 = cg * 12;
    const int gpnt = pbase + p;

    for (int m = 0; m < 3; ++m) {
        const float* W = (m == 0) ? Wq : ((m == 1) ? Wk : Wv);
        __syncthreads();  // sfeat ready (m=0) / prior-phase sout reduce done
        for (int i = t; i < CC * 24; i += 256) {
            int i4 = i * 4;
            int j = i4 / CC, c = i4 % CC;
            *(float4*)(sW + j * 100 + c) = *(const float4*)(W + j * CC + c);
        }
        __syncthreads();

        float acc[12];
        #pragma unroll
        for (int u = 0; u < 12; ++u) acc[u] = 0.f;

        #pragma unroll 4
        for (int j = 0; j < CC; ++j) {
            float f = sfeat[p * 100 + j];          // broadcast within 8-lane group
            const float* wr = sW + j * 100 + c0;
            float4 w0 = *(const float4*)(wr);
            float4 w1 = *(const float4*)(wr + 4);
            float4 w2 = *(const float4*)(wr + 8);
            acc[0] = fmaf(f, w0.x, acc[0]);  acc[1] = fmaf(f, w0.y, acc[1]);
            acc[2] = fmaf(f, w0.z, acc[2]);  acc[3] = fmaf(f, w0.w, acc[3]);
            acc[4] = fmaf(f, w1.x, acc[4]);  acc[5] = fmaf(f, w1.y, acc[5]);
            acc[6] = fmaf(f, w1.z, acc[6]);  acc[7] = fmaf(f, w1.w, acc[7]);
            acc[8] = fmaf(f, w2.x, acc[8]);  acc[9] = fmaf(f, w2.y, acc[9]);
            acc[10] = fmaf(f, w2.z, acc[10]); acc[11] = fmaf(f, w2.w, acc[11]);
        }

        if (m == 2) {
            // v: add bias, write straight to global (3x float4)
            if (gpnt < N) {
                float o[12];
                #pragma unroll
                for (int u = 0; u < 12; ++u) o[u] = acc[u] + bv[c0 + u];
                float* dst = v_ws + (size_t)gpnt * CC + c0;
                *(float4*)(dst)     = make_float4(o[0], o[1], o[2], o[3]);
                *(float4*)(dst + 4) = make_float4(o[4], o[5], o[6], o[7]);
                *(float4*)(dst + 8) = make_float4(o[8], o[9], o[10], o[11]);
            }
        } else {
            // q/k: relu(bn(.)) to LDS, then 6-dim Ww1 reduction
            const float* bb = m ? bk : bq;
            const float* gg = m ? gk : gq;
            const float* be = m ? betak : betaq;
            #pragma unroll
            for (int u = 0; u < 12; ++u)
                sout[p * 100 + c0 + u] =
                    fmaxf(0.f, fmaf(acc[u] + bb[c0 + u], gg[c0 + u] * BN_INV, be[c0 + u]));
            __syncthreads();
            if (t < TP * GG) {
                int pp = t / GG, g = t % GG;
                const float* srow = sout + pp * 100;
                float a = 0.f;
                #pragma unroll 8
                for (int c = 0; c < CC; ++c)
                    a = fmaf(srow[c], Ww1[c * GG + g], a);
                if (pbase + pp < N) {
                    float* dst = m ? KW1 : qW1;
                    dst[(size_t)(pbase + pp) * 8 + g] = a;
                }
            }
            // next phase's leading __syncthreads protects sout
        }
    }
}

// ---------------- kernel 2: attention. 256 thr = 4 waves = 4 points ----------------
// Wp2/Wpw/cvec staged once per block (single barrier); then fully wave-private.
__global__ __launch_bounds__(256) void attn_kernel(
    const float* __restrict__ coord, const int* __restrict__ ref,
    const float* __restrict__ Wp1, const float* __restrict__ bp1, const float* __restrict__ gp, const float* __restrict__ betap,
    const float* __restrict__ bp2,
    const float* __restrict__ gw, const float* __restrict__ betaw,
    const float* __restrict__ Ww2, const float* __restrict__ bw2,
    const float* __restrict__ v_ws, const float* __restrict__ KW1, const float* __restrict__ qW1,
    const float* __restrict__ WpwT, const float* __restrict__ cvec, const float* __restrict__ Wp2,
    float* __restrict__ out, int N)
{
    __shared__ __align__(16) float sWp2[CC * 100];   // raw layout [j][c], row pad 100
    __shared__ __align__(16) float sWpw[GG * 100 + 8];
    __shared__ __align__(16) float scvec[8];
    __shared__ __align__(16) float sh[4][SS * 100];  // h[s][c] per wave
    __shared__ __align__(16) float swt[4][SS * 8];   // logits -> weights per wave
    __shared__ __align__(16) float sHs[4][GG * 100]; // Hsum[g][c] per wave
    __shared__ __align__(16) float spos[4][SS * 4];

    const int t = threadIdx.x;

    // block-wide stage-in
    for (int i = t; i < CC * 24; i += 256) {
        int i4 = i * 4;
        int j = i4 / CC, c = i4 % CC;
        *(float4*)(sWp2 + j * 100 + c) = *(const float4*)(Wp2 + j * CC + c);
    }
    if (t < 144) {
        int i4 = t * 4;
        int g = i4 / CC, j = i4 % CC;
        *(float4*)(sWpw + g * 100 + j) = *(const float4*)(WpwT + g * CC + j);
    }
    if (t < GG) scvec[t] = cvec[t];
    __syncthreads();   // ONLY block barrier

    const int w = t >> 6, lane = t & 63;
    const int n = blockIdx.x * 4 + w;
    if (n >= N) return;

    float* shw  = sh[w];
    float* swtw = swt[w];
    float* sHsw = sHs[w];
    float* sposw = spos[w];

    const int s16 = lane & 15;
    const int idxreg = ref[n * SS + s16];

    if (lane < SS) {
        float cx = coord[n * 3 + 0];
        float cy = coord[n * 3 + 1];
        float cz = coord[n * 3 + 2];
        int j = idxreg;
        sposw[lane * 4 + 0] = coord[j * 3 + 0] - cx;
        sposw[lane * 4 + 1] = coord[j * 3 + 1] - cy;
        sposw[lane * 4 + 2] = coord[j * 3 + 2] - cz;
    }

    const int c0 = lane;               // 0..63
    const int c1 = 64 + (lane & 31);   // 64..95 (lanes>=32 redundant)

    const float w1x0 = Wp1[c0], w1y0 = Wp1[CC + c0], w1z0 = Wp1[2 * CC + c0];
    const float b10 = bp1[c0], sp0 = gp[c0] * BN_INV, bt0 = betap[c0];
    const float w1x1 = Wp1[c1], w1y1 = Wp1[CC + c1], w1z1 = Wp1[2 * CC + c1];
    const float b11 = bp1[c1], sp1 = gp[c1] * BN_INV, bt1 = betap[c1];

    // ---- stage 1: h; keep in registers AND LDS ----
    float hr0[SS], hr1[SS];
    #pragma unroll 4
    for (int s = 0; s < SS; ++s) {
        float px = sposw[s * 4 + 0];
        float py = sposw[s * 4 + 1];
        float pz = sposw[s * 4 + 2];
        float h0 = fmaf(px, w1x0, fmaf(py, w1y0, fmaf(pz, w1z0, b10)));
        h0 = fmaxf(0.f, fmaf(h0, sp0, bt0));
        hr0[s] = h0;
        shw[s * 100 + c0] = h0;
        float h1 = fmaf(px, w1x1, fmaf(py, w1y1, fmaf(pz, w1z1, b11)));
        h1 = fmaxf(0.f, fmaf(h1, sp1, bt1));
        hr1[s] = h1;
        if (lane < 32) shw[s * 100 + c1] = h1;
    }

    // ---- stage 2: logits. 4 lanes per neighbor (qq = lane>>4 owns 24 channels) ----
    {
        const int qq = lane >> 4;
        const float* hrow = shw + s16 * 100 + qq * 24;
        float hg[24];
        #pragma unroll
        for (int u = 0; u < 6; ++u) {
            float4 hv = *(const float4*)(hrow + 4 * u);
            hg[4 * u + 0] = hv.x; hg[4 * u + 1] = hv.y;
            hg[4 * u + 2] = hv.z; hg[4 * u + 3] = hv.w;
        }
        float acc[GG];
        #pragma unroll
        for (int g = 0; g < GG; ++g) {
            const float* wr = sWpw + g * 100 + qq * 24;
            float a = 0.f;
            #pragma unroll
            for (int u = 0; u < 6; ++u) {
                float4 wv = *(const float4*)(wr + 4 * u);
                a = fmaf(hg[4 * u + 0], wv.x, fmaf(hg[4 * u + 1], wv.y,
                    fmaf(hg[4 * u + 2], wv.z, fmaf(hg[4 * u + 3], wv.w, a))));
            }
            acc[g] = a;
        }
        #pragma unroll
        for (int g = 0; g < GG; ++g) {
            acc[g] += __shfl_xor(acc[g], 16);
            acc[g] += __shfl_xor(acc[g], 32);
        }
        if (lane < SS) {
            const int jj = idxreg;
            float4 kA = *(const float4*)(KW1 + (size_t)jj * 8);
            float2 kB = *(const float2*)(KW1 + (size_t)jj * 8 + 4);
            float4 qA = *(const float4*)(qW1 + (size_t)n * 8);
            float2 qB = *(const float2*)(qW1 + (size_t)n * 8 + 4);
            float tv[GG];
            tv[0] = acc[0] + kA.x - qA.x + scvec[0];
            tv[1] = acc[1] + kA.y - qA.y + scvec[1];
            tv[2] = acc[2] + kA.z - qA.z + scvec[2];
            tv[3] = acc[3] + kA.w - qA.w + scvec[3];
            tv[4] = acc[4] + kB.x - qB.x + scvec[4];
            tv[5] = acc[5] + kB.y - qB.y + scvec[5];
            float a6[GG];
            #pragma unroll
            for (int g = 0; g < GG; ++g)
                a6[g] = fmaxf(0.f, fmaf(tv[g], gw[g] * BN_INV, betaw[g]));
            #pragma unroll
            for (int gg = 0; gg < GG; ++gg) {
                float l = bw2[gg];
                #pragma unroll
                for (int g2 = 0; g2 < GG; ++g2)
                    l = fmaf(a6[g2], Ww2[g2 * GG + gg], l);
                swtw[lane * 8 + gg] = l;
            }
        }
    }

    // ---- stage 3: softmax over s (6 lanes) ----
    if (lane < GG) {
        const int g = lane;
        float m = -1e30f;
        #pragma unroll
        for (int s = 0; s < SS; ++s) m = fmaxf(m, swtw[s * 8 + g]);
        float e[SS];
        float sum = 0.f;
        #pragma unroll
        for (int s = 0; s < SS; ++s) { e[s] = __expf(swtw[s * 8 + g] - m); sum += e[s]; }
        float r = 1.f / sum;
        #pragma unroll
        for (int s = 0; s < SS; ++s) swtw[s * 8 + g] = e[s] * r;
    }

    // ---- stage 4: Hsum[g][c] from register h ----
    {
        float hs0[GG] = {0.f, 0.f, 0.f, 0.f, 0.f, 0.f};
        float hs1[GG] = {0.f, 0.f, 0.f, 0.f, 0.f, 0.f};
        #pragma unroll 4
        for (int s = 0; s < SS; ++s) {
            float4 wa = *(const float4*)(swtw + s * 8);
            float2 wb = *(const float2*)(swtw + s * 8 + 4);
            float h0 = hr0[s], h1 = hr1[s];
            hs0[0] = fmaf(wa.x, h0, hs0[0]); hs1[0] = fmaf(wa.x, h1, hs1[0]);
            hs0[1] = fmaf(wa.y, h0, hs0[1]); hs1[1] = fmaf(wa.y, h1, hs1[1]);
            hs0[2] = fmaf(wa.z, h0, hs0[2]); hs1[2] = fmaf(wa.z, h1, hs1[2]);
            hs0[3] = fmaf(wa.w, h0, hs0[3]); hs1[3] = fmaf(wa.w, h1, hs1[3]);
            hs0[4] = fmaf(wb.x, h0, hs0[4]); hs1[4] = fmaf(wb.x, h1, hs1[4]);
            hs0[5] = fmaf(wb.y, h0, hs0[5]); hs1[5] = fmaf(wb.y, h1, hs1[5]);
        }
        #pragma unroll
        for (int g = 0; g < GG; ++g) {
            sHsw[g * 100 + c0] = hs0[g];
            if (lane < 32) sHsw[g * 100 + c1] = hs1[g];
        }
    }

    // ---- stage 5: out[c] = sum_s v[j_s][c]*w[s][g] + Hsum[g]@Wp2[:,c] + bp2[c] ----
    {
        const int g0 = lane >> 4;
        const int g1 = 4 + ((lane & 31) >> 4);
        float acc0 = bp2[c0];
        float acc1 = bp2[c1];
        #pragma unroll 4
        for (int s = 0; s < SS; ++s) {
            int jj = __shfl(idxreg, s);
            float w0 = swtw[s * 8 + g0];
            float w1 = swtw[s * 8 + g1];
            acc0 = fmaf(v_ws[(size_t)jj * CC + c0], w0, acc0);
            acc1 = fmaf(v_ws[(size_t)jj * CC + c1], w1, acc1);
        }
        // j-major: Wp2 reads coalesced across lanes (2-way = free), Hsum broadcast
        #pragma unroll 8
        for (int j = 0; j < CC; j += 2) {
            float2 h0 = *(const float2*)(sHsw + g0 * 100 + j);
            float2 h1 = *(const float2*)(sHsw + g1 * 100 + j);
            acc0 = fmaf(h0.x, sWp2[j * 100 + c0], acc0);
            acc0 = fmaf(h0.y, sWp2[(j + 1) * 100 + c0], acc0);
            acc1 = fmaf(h1.x, sWp2[j * 100 + c1], acc1);
            acc1 = fmaf(h1.y, sWp2[(j + 1) * 100 + c1], acc1);
        }
        out[(size_t)n * CC + c0] = acc0;
        if (lane < 32) out[(size_t)n * CC + c1] = acc1;
    }
}

extern "C" void kernel_launch(void* const* d_in, const int* in_sizes, int n_in,
                              void* d_out, int out_size, void* d_ws, size_t ws_size,
                              hipStream_t stream) {
    const float* feat  = (const float*)d_in[0];
    const float* coord = (const float*)d_in[1];
    const int*   ref   = (const int*)d_in[2];
    const float* Wq = (const float*)d_in[3],  *bq = (const float*)d_in[4],  *gq = (const float*)d_in[5],  *betaq = (const float*)d_in[6];
    const float* Wk = (const float*)d_in[7],  *bk = (const float*)d_in[8],  *gk = (const float*)d_in[9],  *betak = (const float*)d_in[10];
    const float* Wv = (const float*)d_in[11], *bv = (const float*)d_in[12];
    const float* Wp1 = (const float*)d_in[13], *bp1 = (const float*)d_in[14], *gp = (const float*)d_in[15], *betap = (const float*)d_in[16];
    const float* Wp2 = (const float*)d_in[17], *bp2 = (const float*)d_in[18];
    const float* Ww1 = (const float*)d_in[19], *bw1 = (const float*)d_in[20], *gw = (const float*)d_in[21], *betaw = (const float*)d_in[22];
    const float* Ww2 = (const float*)d_in[23], *bw2 = (const float*)d_in[24];

    const int N = in_sizes[0] / CC;   // 50000

    // workspace layout (fp32, ~21.4 MB)
    float* wsf  = (float*)d_ws;
    float* KW1  = wsf;                               // N*8
    float* qW1  = KW1 + (size_t)N * 8;               // N*8
    float* WpwT = qW1 + (size_t)N * 8;               // 6*96 (=576, 16B-mult)
    float* cvec = WpwT + GG * CC;                    // 6 (pad 32)
    float* v_ws = cvec + 32;                         // N*96

    precompute_kernel<<<dim3(3), dim3(256), 0, stream>>>(
        Wp2, Ww1, bp2, bw1, WpwT, cvec);

    qkv_kernel<<<dim3((N + TP - 1) / TP), dim3(256), 0, stream>>>(
        feat, Wq, bq, gq, betaq, Wk, bk, gk, betak, Wv, bv, Ww1,
        v_ws, KW1, qW1, N);

    attn_kernel<<<dim3((N + 3) / 4), dim3(256), 0, stream>>>(
        coord, ref, Wp1, bp1, gp, betap, bp2, gw, betaw, Ww2, bw2,
        v_ws, KW1, qW1, WpwT, cvec, Wp2, (float*)d_out, N);
}